// Round 19
// baseline (326.732 us; speedup 1.0000x reference)
//
#include <hip/hip_runtime.h>
#include <hip/hip_bf16.h>

typedef __hip_bfloat16 bf16;

#define BB 16
#define LL 512
#define DD 512
#define NHH 8
#define HDD 64
#define TT 17
#define MM (BB*LL)
#define RCH 8
#define RCK 65

typedef __attribute__((ext_vector_type(8))) short bfrag;
typedef __attribute__((ext_vector_type(4))) float ffrag;
typedef __attribute__((ext_vector_type(8))) unsigned short us8;

struct Params {
  const int* tokens;
  const float* emb;
  const float *sat_qw, *sat_qb, *sat_kw, *sat_kb, *sat_vw, *sat_vb, *sat_ow, *sat_ob;
  const float *rel_qw, *rel_qb, *rel_kw, *rel_kb, *rel_vw, *rel_vb, *rel_ow, *rel_ob;
  const float *ln_sat_w, *ln_sat_b, *ln_rel_w, *ln_rel_b, *ofc_w, *ofc_b;
  bf16 *ebf, *qkv, *kvbuf, *KeVe, *qbuf, *ctxbf, *WtAll, *WtO, *WtLog;
  float *s, *KsVs, *qr, *Ksr, *Vsr, *pws, *out;
  int* cnt;
};

static __device__ __forceinline__ void gld16(const void* g, void* l){
  __builtin_amdgcn_global_load_lds((const __attribute__((address_space(1))) void*)g,
                                   (__attribute__((address_space(3))) void*)l, 16, 0, 0);
}
static __device__ __forceinline__ float us2f(unsigned short u){
  unsigned int v = ((unsigned int)u) << 16;
  float f; __builtin_memcpy(&f, &v, 4); return f;
}
static __device__ __forceinline__ float hsum8(float v){
  v += __shfl_xor(v, 1); v += __shfl_xor(v, 2); v += __shfl_xor(v, 4);
  return v;
}

// ---------------- init: embed + atomic mean into s (u<256) | weight prep ----------------
__global__ __launch_bounds__(256) void k_init(Params P){
  __shared__ __align__(16) char sm[8192];
  int u = blockIdx.x, t = threadIdx.x;
  if (u < 256){
    int* toks = (int*)sm;
    int b = u >> 4, lc = u & 15;
    if (t < 32) toks[t] = P.tokens[b*LL + lc*32 + t];
    __syncthreads();
    bf16* eb = P.ebf + ((size_t)b*LL + lc*32)*DD;
    for (int d = t; d < DD; d += 256){
      float acc = 0.f;
      #pragma unroll 4
      for (int l = 0; l < 32; l++){
        float v = P.emb[(size_t)toks[l]*DD + d];
        eb[(size_t)l*DD + d] = __float2bfloat16(v);
        acc += v;
      }
      atomicAdd(&P.s[(size_t)b*DD + d], acc * (1.0f/LL));  // s pre-zeroed by memset
    }
    return;
  }
  int w = u - 256;
  int z = w >> 8, xy = w & 255;
  int tx = t & 31, ty = t >> 5;
  if (z == 6){
    int i = (xy << 8) + t;
    int row = i >> 9, k = i & 511;
    P.WtLog[i] = __float2bfloat16(row < TT ? P.ofc_w[(size_t)k*TT + row] : 0.f);
    return;
  }
  float (*tile)[33] = (float(*)[33])sm;
  const float* in = (z==0)?P.sat_qw:(z==1)?P.sat_kw:(z==2)?P.sat_vw:
                    (z==3)?P.rel_kw:(z==4)?P.rel_vw:P.sat_ow;
  bf16* out = (z<5) ? (P.WtAll + (size_t)z*512*512) : P.WtO;
  int bx = (xy & 15)*32, by = (xy >> 4)*32;
  #pragma unroll
  for (int j = 0; j < 32; j += 8)
    tile[ty + j][tx] = in[(size_t)(by + ty + j)*DD + bx + tx];
  __syncthreads();
  #pragma unroll
  for (int j = 0; j < 32; j += 8)
    out[(size_t)(bx + ty + j)*DD + by + tx] = __float2bfloat16(tile[tx][ty + j]);
}

// ---------------- merged: QKV-c0 GEMM (blocks 0..767) + c0 s-projections (768..847) ----
// Both bodies INLINE (r16 lesson: device-fn indirection doubles VGPR).
__global__ __launch_bounds__(256)
void k_qkvsp(Params P){
  __shared__ __align__(16) char smu[17408];
  int t = threadIdx.x;
  if (blockIdx.x < 768){
    const int K = 512;
    bf16* As = (bf16*)smu;
    bf16* Bs = (bf16*)(smu + 8192);
    const bf16* __restrict__ A  = P.ebf;
    const bf16* __restrict__ Wt = P.WtAll;
    int wave = t >> 6, lane = t & 63;
    int id = blockIdx.x;
    int bm = (((id & 7) << 3) | ((id >> 3) & 7)) * 128;
    int bn = (id >> 6) * 128;
    int wm = (wave & 1) * 64, wn = (wave >> 1) * 64;
    ffrag acc[4][4];
    #pragma unroll
    for (int i = 0; i < 4; i++)
      #pragma unroll
      for (int j = 0; j < 4; j++) acc[i][j] = (ffrag){0.f,0.f,0.f,0.f};
    int srow = t >> 2;
    int scol = ((((t & 3) - ((t >> 3) & 3)) & 3)) * 8;   // conflict-free (r13/r15)
    const bf16* gA = A  + (size_t)(bm + srow)*K + scol;
    const bf16* gB = Wt + (size_t)(bn + srow)*K + scol;
    char* lA = (char*)As + 16*t;
    char* lB = (char*)Bs + 16*t;
    int q = lane >> 4, r = lane & 15;
    int cs = (((q + (r >> 1)) & 3)) * 8;
    for (int k0 = 0; k0 < K; k0 += 32){
      gld16(gA + k0,          lA);
      gld16(gA + 64*K + k0,   lA + 4096);
      gld16(gB + k0,          lB);
      gld16(gB + 64*K + k0,   lB + 4096);
      __syncthreads();
      bfrag af[4], bfv[4];
      #pragma unroll
      for (int i = 0; i < 4; i++){
        af[i]  = *(const bfrag*)(As + (wm + i*16 + r)*32 + cs);
        bfv[i] = *(const bfrag*)(Bs + (wn + i*16 + r)*32 + cs);
      }
      #pragma unroll
      for (int i = 0; i < 4; i++)
        #pragma unroll
        for (int j = 0; j < 4; j++)
          acc[i][j] = __builtin_amdgcn_mfma_f32_16x16x32_bf16(af[i], bfv[j], acc[i][j], 0, 0, 0);
      __syncthreads();
    }
    #pragma unroll
    for (int i = 0; i < 4; i++){
      #pragma unroll
      for (int j = 0; j < 4; j++){
        int row = bm + wm + i*16 + q*4;
        int col = bn + wn + j*16 + r;
        const float* bp = (col < 512) ? P.sat_qb : (col < 1024) ? P.sat_kb : P.sat_vb;
        float bias = bp[col & 511];
        bf16* D; int ld;
        if (col < 512){ D = P.qbuf + (size_t)row*512 + col;        ld = 512; }
        else          { D = P.KeVe + (size_t)row*1024 + (col-512); ld = 1024; }
        #pragma unroll
        for (int g = 0; g < 4; g++)
          D[(size_t)g*ld] = __float2bfloat16(acc[i][j][g] + bias);
      }
    }
    return;
  }
  // ---- c0 s-projections: 80 blocks, split-k, A = P.s (global, from atomics) ----
  float (*part)[32][17] = (float(*)[32][17])smu;
  int u = blockIdx.x - 768;
  int n = t & 31, kg = t >> 5;
  int wi = u >> 4, ch = u & 15;
  const float* W  = (wi==0)?P.sat_kw:(wi==1)?P.sat_vw:(wi==2)?P.rel_qw:
                    (wi==3)?P.rel_kw:P.rel_vw;
  const float* bs = (wi==0)?P.sat_kb:(wi==1)?P.sat_vb:(wi==2)?P.rel_qb:
                    (wi==3)?P.rel_kb:P.rel_vb;
  float* O  = (wi==0)?P.KsVs:(wi==1)?(P.KsVs+512):(wi==2)?P.qr:(wi==3)?P.Ksr:P.Vsr;
  int ldc   = (wi<2) ? 1024 : 512;
  int col = ch*32 + n;
  float acc2[16];
  #pragma unroll
  for (int m = 0; m < 16; m++) acc2[m] = 0.f;
  const float* Wp = W + (size_t)(kg*64)*512 + col;
  const float* Ap = P.s + kg*64;
  for (int k = 0; k < 64; k++){
    float w = Wp[(size_t)k*512];
    #pragma unroll
    for (int m = 0; m < 16; m++) acc2[m] = fmaf(Ap[m*512 + k], w, acc2[m]);
  }
  #pragma unroll
  for (int m = 0; m < 16; m++) part[kg][n][m] = acc2[m];
  __syncthreads();
  for (int o = t; o < 512; o += 256){
    int m = o >> 5, nn = o & 31;
    float v = 0.f;
    #pragma unroll
    for (int g = 0; g < 8; g++) v += part[g][nn][m];
    O[(size_t)m*ldc + ch*32 + nn] = v + bs[ch*32 + nn];
  }
}

// ---------------- c1 s-projections (A = P.s, written by reltail2 last blocks) ----------------
__global__ __launch_bounds__(256)
void k_sproj1(Params P){
  __shared__ float part[8][32][17];
  int t = threadIdx.x;
  int n = t & 31, kg = t >> 5;
  int wi = blockIdx.x >> 4, ch = blockIdx.x & 15;   // wi in 0..1
  const float* W  = (wi==0)?P.sat_kw:P.sat_vw;
  const float* bs = (wi==0)?P.sat_kb:P.sat_vb;
  float* O  = (wi==0)?P.KsVs:(P.KsVs+512);
  int col = ch*32 + n;
  float acc[16];
  #pragma unroll
  for (int m = 0; m < 16; m++) acc[m] = 0.f;
  const float* Wp = W + (size_t)(kg*64)*512 + col;
  const float* Ap = P.s + kg*64;
  for (int k = 0; k < 64; k++){
    float w = Wp[(size_t)k*512];
    #pragma unroll
    for (int m = 0; m < 16; m++) acc[m] = fmaf(Ap[m*512 + k], w, acc[m]);
  }
  #pragma unroll
  for (int m = 0; m < 16; m++) part[kg][n][m] = acc[m];
  __syncthreads();
  for (int o = t; o < 512; o += 256){
    int m = o >> 5, nn = o & 31;
    float v = 0.f;
    #pragma unroll
    for (int g = 0; g < 8; g++) v += part[g][nn][m];
    O[(size_t)m*1024 + ch*32 + nn] = v + bs[ch*32 + nn];
  }
}

// ---------------- MFMA GEMM (standalone body — r16 VGPR lesson) ----------------
__global__ __launch_bounds__(256)
void k_gemm(Params P, const bf16* __restrict__ A, const bf16* __restrict__ Wt,
            const float* b0, const float* b1, const float* b2, const float* b3,
            const float* b4,
            bf16* D0, int ld0, bf16* D1, int ld1, int split){
  const int K = 512;
  __shared__ bf16 As[128*32];
  __shared__ bf16 Bs[128*32];
  int t = threadIdx.x;
  int wave = t >> 6, lane = t & 63;
  int id = blockIdx.x;
  int bm = (((id & 7) << 3) | ((id >> 3) & 7)) * 128;
  int bn = (id >> 6) * 128;
  int wm = (wave & 1) * 64, wn = (wave >> 1) * 64;
  ffrag acc[4][4];
  #pragma unroll
  for (int i = 0; i < 4; i++)
    #pragma unroll
    for (int j = 0; j < 4; j++) acc[i][j] = (ffrag){0.f,0.f,0.f,0.f};

  int srow = t >> 2;
  int scol = ((((t & 3) - ((t >> 3) & 3)) & 3)) * 8;
  const bf16* gA = A  + (size_t)(bm + srow)*K + scol;
  const bf16* gB = Wt + (size_t)(bn + srow)*K + scol;
  char* lA = (char*)As + 16*t;
  char* lB = (char*)Bs + 16*t;
  int q = lane >> 4, r = lane & 15;
  int cs = (((q + (r >> 1)) & 3)) * 8;

  for (int k0 = 0; k0 < K; k0 += 32){
    gld16(gA + k0,          lA);
    gld16(gA + 64*K + k0,   lA + 4096);
    gld16(gB + k0,          lB);
    gld16(gB + 64*K + k0,   lB + 4096);
    __syncthreads();
    bfrag af[4], bfv[4];
    #pragma unroll
    for (int i = 0; i < 4; i++){
      af[i]  = *(const bfrag*)(As + (wm + i*16 + r)*32 + cs);
      bfv[i] = *(const bfrag*)(Bs + (wn + i*16 + r)*32 + cs);
    }
    #pragma unroll
    for (int i = 0; i < 4; i++)
      #pragma unroll
      for (int j = 0; j < 4; j++)
        acc[i][j] = __builtin_amdgcn_mfma_f32_16x16x32_bf16(af[i], bfv[j], acc[i][j], 0, 0, 0);
    __syncthreads();
  }
  #pragma unroll
  for (int i = 0; i < 4; i++){
    #pragma unroll
    for (int j = 0; j < 4; j++){
      int row = bm + wm + i*16 + q*4;
      int col = bn + wn + j*16 + r;
      const float* bp = (col < 512) ? b0 : (col < 1024) ? b1 :
                        (col < 1536) ? b2 : (col < 2048) ? b3 : b4;
      float bias = bp[col & 511];
      bf16* D; int ld;
      if (col < split){ D = D0 + (size_t)row*ld0 + col;         ld = ld0; }
      else            { D = D1 + (size_t)row*ld1 + (col-split); ld = ld1; }
      #pragma unroll
      for (int g = 0; g < 4; g++)
        D[(size_t)g*ld] = __float2bfloat16(acc[i][j][g] + bias);
    }
  }
}

// ---------------- logits: fused LN(c1) phase + masked GEMM ----------------
__global__ __launch_bounds__(256) void k_logits(Params P){
  const int K = 512;
  __shared__ bf16 As[128*32];
  __shared__ bf16 Bs[128*32];
  int t = threadIdx.x;
  int wave = t >> 6, lane = t & 63;
  int bm = blockIdx.x * 128;
  // ---- phase 1: relu+LN rows bm..bm+127 (aout -> hbf), wave-per-row ----
  {
    const bf16* aout = P.qkv;   // c1 out-proj result
    bf16* hbf = P.ebf;
    int off = lane*8;
    for (int rr = 0; rr < 32; rr++){
      int row = bm + wave*32 + rr;
      us8 x8 = *(const us8*)(aout + (size_t)row*DD + off);
      float v[8], sum = 0.f;
      #pragma unroll
      for (int g = 0; g < 8; g++){ v[g] = fmaxf(us2f(x8[g]), 0.f); sum += v[g]; }
      #pragma unroll
      for (int o = 32; o; o >>= 1) sum += __shfl_xor(sum, o);
      float u = sum * (1.0f/DD);
      float d[8], var = 0.f;
      #pragma unroll
      for (int g = 0; g < 8; g++){ d[g] = v[g] - u; var += d[g]*d[g]; }
      #pragma unroll
      for (int o = 32; o; o >>= 1) var += __shfl_xor(var, o);
      float inv = rsqrtf(var * (1.0f/DD) + 1e-12f);
      bf16 ob[8];
      #pragma unroll
      for (int g = 0; g < 8; g++)
        ob[g] = __float2bfloat16(P.ln_sat_w[off+g]*d[g]*inv + P.ln_sat_b[off+g]);
      *(us8*)(hbf + (size_t)row*DD + off) = *(const us8*)ob;
    }
  }
  __syncthreads();
  // ---- phase 2: masked logits GEMM (all 4 waves, 32 rows each; cols<32) ----
  int wm = wave * 32;
  ffrag acc[2][2];
  #pragma unroll
  for (int i = 0; i < 2; i++){ acc[i][0] = (ffrag){0,0,0,0}; acc[i][1] = (ffrag){0,0,0,0}; }
  int srow = t >> 2;
  int scol = ((((t & 3) - ((t >> 3) & 3)) & 3)) * 8;
  const bf16* gA = P.ebf + (size_t)(bm + srow)*K + scol;
  const bf16* gB = P.WtLog + (size_t)srow*K + scol;
  char* lA = (char*)As + 16*t;
  char* lB = (char*)Bs + 16*t;
  int q = lane >> 4, r = lane & 15;
  int cs = (((q + (r >> 1)) & 3)) * 8;

  for (int k0 = 0; k0 < K; k0 += 32){
    gld16(gA + k0,          lA);
    gld16(gA + 64*K + k0,   lA + 4096);
    gld16(gB + k0,          lB);
    gld16(gB + 64*K + k0,   lB + 4096);
    __syncthreads();
    bfrag bf0 = *(const bfrag*)(Bs + (r)*32 + cs);
    bfrag bf1 = *(const bfrag*)(Bs + (16 + r)*32 + cs);
    #pragma unroll
    for (int i = 0; i < 2; i++){
      bfrag af = *(const bfrag*)(As + (wm + i*16 + r)*32 + cs);
      acc[i][0] = __builtin_amdgcn_mfma_f32_16x16x32_bf16(af, bf0, acc[i][0], 0, 0, 0);
      acc[i][1] = __builtin_amdgcn_mfma_f32_16x16x32_bf16(af, bf1, acc[i][1], 0, 0, 0);
    }
    __syncthreads();
  }
  #pragma unroll
  for (int i = 0; i < 2; i++)
    #pragma unroll
    for (int j = 0; j < 2; j++){
      int row = bm + wm + i*16 + q*4;
      int col = j*16 + r;
      if (col < TT){
        float bv = P.ofc_b[col];
        #pragma unroll
        for (int g = 0; g < 4; g++)
          P.out[(size_t)(row + g)*TT + col] = acc[i][j][g] + bv;
      }
    }
}

// ---------------- sat attention: wave/token, us8 loads ----------------
__global__ __launch_bounds__(256)
void k_sat(Params P, const bf16* qp, int sq, const bf16* kp, const bf16* vp, int skv){
  int tok = blockIdx.x*4 + (threadIdx.x >> 6);
  int l = threadIdx.x & 63;
  int b = tok >> 9, li = tok & 511;
  int off = l*8;
  int t0 = (b << 9) | ((li + 1) & 511);
  int t2 = (b << 9) | (li == 0 ? 511 : 0);
  float qf[8];
  { us8 q8 = *(const us8*)(qp + (size_t)tok*sq + off);
    #pragma unroll
    for (int g = 0; g < 8; g++) qf[g] = us2f(q8[g]); }
  float sc[5];
  int rows[3] = {t0, tok, t2};
  #pragma unroll
  for (int j = 0; j < 3; j++){
    us8 k8 = *(const us8*)(kp + (size_t)rows[j]*skv + off);
    float a = 0.f;
    #pragma unroll
    for (int g = 0; g < 8; g++) a += qf[g]*us2f(k8[g]);
    sc[j] = hsum8(a) * 0.125f;
  }
  { us8 k8 = *(const us8*)(P.KeVe + (size_t)tok*1024 + off);
    float a = 0.f;
    #pragma unroll
    for (int g = 0; g < 8; g++) a += qf[g]*us2f(k8[g]);
    sc[3] = hsum8(a) * 0.125f; }
  { const float* ks = P.KsVs + (size_t)b*1024 + off;
    float4 f0 = *(const float4*)ks, f1 = *(const float4*)(ks + 4);
    float a = qf[0]*f0.x + qf[1]*f0.y + qf[2]*f0.z + qf[3]*f0.w
            + qf[4]*f1.x + qf[5]*f1.y + qf[6]*f1.z + qf[7]*f1.w;
    sc[4] = hsum8(a) * 0.125f; }
  float m = fmaxf(fmaxf(fmaxf(sc[0],sc[1]), fmaxf(sc[2],sc[3])), sc[4]);
  float pr[5], den = 0.f;
  #pragma unroll
  for (int j = 0; j < 5; j++){ pr[j] = __expf(sc[j]-m); den += pr[j]; }
  float inv = 1.0f/den;
  float o[8];
  #pragma unroll
  for (int g = 0; g < 8; g++) o[g] = 0.f;
  #pragma unroll
  for (int j = 0; j < 3; j++){
    us8 v8 = *(const us8*)(vp + (size_t)rows[j]*skv + off);
    #pragma unroll
    for (int g = 0; g < 8; g++) o[g] += pr[j]*us2f(v8[g]);
  }
  { us8 v8 = *(const us8*)(P.KeVe + (size_t)tok*1024 + 512 + off);
    #pragma unroll
    for (int g = 0; g < 8; g++) o[g] += pr[3]*us2f(v8[g]); }
  { const float* vs = P.KsVs + (size_t)b*1024 + 512 + off;
    float4 f0 = *(const float4*)vs, f1 = *(const float4*)(vs + 4);
    o[0] += pr[4]*f0.x; o[1] += pr[4]*f0.y; o[2] += pr[4]*f0.z; o[3] += pr[4]*f0.w;
    o[4] += pr[4]*f1.x; o[5] += pr[4]*f1.y; o[6] += pr[4]*f1.z; o[7] += pr[4]*f1.w; }
  bf16 ob[8];
  #pragma unroll
  for (int g = 0; g < 8; g++) ob[g] = __float2bfloat16(o[g]*inv);
  *(us8*)(P.ctxbf + (size_t)tok*DD + off) = *(const us8*)ob;
}

// ---------------- wave-per-row relu+LN (c0), bf16 ----------------
__global__ __launch_bounds__(256) void k_ln(Params P, const bf16* X, bf16* Y){
  int row = blockIdx.x*4 + (threadIdx.x >> 6);
  int lane = threadIdx.x & 63;
  int off = lane*8;
  us8 x8 = *(const us8*)(X + (size_t)row*DD + off);
  float v[8], sum = 0.f;
  #pragma unroll
  for (int g = 0; g < 8; g++){ v[g] = fmaxf(us2f(x8[g]), 0.f); sum += v[g]; }
  #pragma unroll
  for (int o = 32; o; o >>= 1) sum += __shfl_xor(sum, o);
  float u = sum * (1.0f/DD);
  float d[8], var = 0.f;
  #pragma unroll
  for (int g = 0; g < 8; g++){ d[g] = v[g] - u; var += d[g]*d[g]; }
  #pragma unroll
  for (int o = 32; o; o >>= 1) var += __shfl_xor(var, o);
  float inv = rsqrtf(var * (1.0f/DD) + 1e-12f);
  bf16 ob[8];
  #pragma unroll
  for (int g = 0; g < 8; g++)
    ob[g] = __float2bfloat16(P.ln_sat_w[off+g]*d[g]*inv + P.ln_sat_b[off+g]);
  *(us8*)(Y + (size_t)row*DD + off) = *(const us8*)ob;
}

// ---------------- rel attention partials ----------------
__global__ __launch_bounds__(256) void k_relp(Params P){
  __shared__ __align__(16) char sm[4096];
  int u = blockIdx.x, t = threadIdx.x;
  int ch = u & 7, hh = (u >> 3) & 7, b = u >> 6;
  float* qs   = (float*)sm;
  float* sc   = (float*)(sm + 256);
  float* red  = (float*)(sm + 1024);
  float (*part)[64] = (float(*)[64])(sm + 2048);
  int base = hh * HDD;
  int j0 = ch * RCK;
  int nk = min(513 - j0, RCK);
  if (t < 64) qs[t] = P.qr[(size_t)b*DD + base + t];
  __syncthreads();
  if (t < nk){
    int j = j0 + t;
    float a = 0.f;
    if (j == 0){
      const float* kr = P.Ksr + (size_t)b*DD + base;
      #pragma unroll
      for (int d = 0; d < 64; d += 4){
        float4 k4 = *(const float4*)(kr + d);
        float4 q4 = *(const float4*)(qs + d);
        a += q4.x*k4.x + q4.y*k4.y + q4.z*k4.z + q4.w*k4.w;
      }
    } else {
      const bf16* kr = P.kvbuf + ((size_t)b*LL + j - 1)*1024 + base;
      #pragma unroll
      for (int d = 0; d < 64; d += 8){
        us8 k8 = *(const us8*)(kr + d);
        #pragma unroll
        for (int g = 0; g < 8; g++) a += qs[d+g] * us2f(k8[g]);
      }
    }
    sc[t] = a * 0.125f;
  }
  __syncthreads();
  red[t] = (t < nk) ? sc[t] : -1e30f; __syncthreads();
  for (int st = 128; st; st >>= 1){ if (t < st) red[t] = fmaxf(red[t], red[t+st]); __syncthreads(); }
  float m = red[0]; __syncthreads();
  if (t < nk) sc[t] = __expf(sc[t] - m);
  __syncthreads();
  red[t] = (t < nk) ? sc[t] : 0.f; __syncthreads();
  for (int st = 128; st; st >>= 1){ if (t < st) red[t] += red[t+st]; __syncthreads(); }
  float l = red[0];
  int d = t & 63, c2 = t >> 6;
  float a = 0.f;
  for (int j = c2; j < nk; j += 4){
    int gj = j0 + j;
    float vv = (gj == 0) ? P.Vsr[(size_t)b*DD + base + d]
                         : __bfloat162float(P.kvbuf[((size_t)b*LL + gj - 1)*1024 + 512 + base + d]);
    a += sc[j] * vv;
  }
  part[c2][d] = a; __syncthreads();
  float* o = P.pws + (((size_t)(b*NHH + hh))*RCH + ch) * 66;
  if (t < 64) o[t] = part[0][t] + part[1][t] + part[2][t] + part[3][t];
  else if (t == 64) o[64] = m;
  else if (t == 65) o[65] = l;
}

// ---------------- rel tail: combine + split-k out-proj; LAST block per row does LN -> s ----
__global__ __launch_bounds__(256) void k_reltail2(Params P){
  __shared__ float crs[512];
  __shared__ float part[8][33];
  __shared__ int lastFlag;
  int b = blockIdx.x >> 4, ch = blockIdx.x & 15;
  int t = threadIdx.x;
  for (int o = t; o < 512; o += 256){
    int hh = o >> 6, d = o & 63;
    const float* p = P.pws + ((size_t)(b*NHH + hh))*RCH*66;
    float M = -1e30f;
    #pragma unroll
    for (int c = 0; c < RCH; c++) M = fmaxf(M, p[c*66 + 64]);
    float den = 0.f, acc = 0.f;
    #pragma unroll
    for (int c = 0; c < RCH; c++){
      float w = __expf(p[c*66 + 64] - M);
      den += w * p[c*66 + 65];
      acc += w * p[c*66 + d];
    }
    crs[o] = acc / den;
  }
  __syncthreads();
  int n = t & 31, kg = t >> 5;
  int col = ch*32 + n;
  const float* Wp = P.rel_ow + (size_t)(kg*64)*512 + col;
  const float* cp = crs + kg*64;
  float a = 0.f;
  for (int k = 0; k < 64; k++) a = fmaf(cp[k], Wp[(size_t)k*512], a);
  part[kg][n] = a;
  __syncthreads();
  if (t < 32){
    float v = P.rel_ob[ch*32 + t];
    #pragma unroll
    for (int g = 0; g < 8; g++) v += part[g][t];
    atomicExch(&P.qr[(size_t)b*DD + ch*32 + t], v);   // device-coherent store (rr)
  }
  __syncthreads();   // all exchanges complete (vmcnt drained) before counter bump
  if (t == 0) lastFlag = (atomicAdd(&P.cnt[b], 1) == 15);
  __syncthreads();
  if (!lastFlag) return;
  // last block for row b: all 512 cols visible via device-coherent reads
  float v0 = atomicAdd(&P.qr[(size_t)b*DD + t],       0.0f);
  float v1 = atomicAdd(&P.qr[(size_t)b*DD + t + 256], 0.0f);
  float w0 = fmaxf(v0, 0.f), w1 = fmaxf(v1, 0.f);
  crs[t] = w0 + w1; __syncthreads();
  for (int st = 128; st; st >>= 1){ if (t < st) crs[t] += crs[t+st]; __syncthreads(); }
  float u = crs[0] * (1.0f/DD); __syncthreads();
  float d0 = w0 - u, d1 = w1 - u;
  crs[t] = d0*d0 + d1*d1; __syncthreads();
  for (int st = 128; st; st >>= 1){ if (t < st) crs[t] += crs[t+st]; __syncthreads(); }
  float inv = rsqrtf(crs[0] * (1.0f/DD) + 1e-12f);
  // s MUST be written — feeds the c1 KsVs projection (round-5 lesson).
  P.s[(size_t)b*DD + t]       = P.ln_rel_w[t]    *d0*inv + P.ln_rel_b[t];
  P.s[(size_t)b*DD + t + 256] = P.ln_rel_w[t+256]*d1*inv + P.ln_rel_b[t+256];
}

extern "C" void kernel_launch(void* const* d_in, const int* in_sizes, int n_in,
                              void* d_out, int out_size, void* d_ws, size_t ws_size,
                              hipStream_t stream) {
  Params P;
  P.tokens  = (const int*)  d_in[0];
  P.emb     = (const float*)d_in[4];
  P.sat_qw  = (const float*)d_in[5];  P.sat_qb = (const float*)d_in[6];
  P.sat_kw  = (const float*)d_in[7];  P.sat_kb = (const float*)d_in[8];
  P.sat_vw  = (const float*)d_in[9];  P.sat_vb = (const float*)d_in[10];
  P.sat_ow  = (const float*)d_in[11]; P.sat_ob = (const float*)d_in[12];
  P.rel_qw  = (const float*)d_in[13]; P.rel_qb = (const float*)d_in[14];
  P.rel_kw  = (const float*)d_in[15]; P.rel_kb = (const float*)d_in[16];
  P.rel_vw  = (const float*)d_in[17]; P.rel_vb = (const float*)d_in[18];
  P.rel_ow  = (const float*)d_in[19]; P.rel_ob = (const float*)d_in[20];
  P.ln_sat_w= (const float*)d_in[21]; P.ln_sat_b= (const float*)d_in[22];
  P.ln_rel_w= (const float*)d_in[23]; P.ln_rel_b= (const float*)d_in[24];
  P.ofc_w   = (const float*)d_in[25]; P.ofc_b  = (const float*)d_in[26];

  char* p = (char*)d_ws;
  auto alloc = [&](size_t bytes) -> char* {
    char* r = p; p += (bytes + 255) & ~(size_t)255; return r;
  };
  const size_t BIGH = (size_t)MM*DD*2;
  P.ebf   = (bf16*) alloc(BIGH);
  P.qkv   = (bf16*) alloc(3*BIGH);
  P.kvbuf = (bf16*) alloc(2*BIGH);
  P.KeVe  = (bf16*) alloc(2*BIGH);
  P.qbuf  = (bf16*) alloc(BIGH);
  P.ctxbf = (bf16*) alloc(BIGH);
  P.WtAll = (bf16*) alloc((size_t)2560*512*2);
  P.WtO   = (bf16*) alloc((size_t)512*512*2);
  P.WtLog = (bf16*) alloc((size_t)128*512*2);
  P.s     = (float*)alloc(BB*DD*4);      // 32 KB, 256-aligned
  P.cnt   = (int*)  alloc(64);           // contiguous after s
  P.KsVs  = (float*)alloc(BB*1024*4);
  P.qr    = (float*)alloc(BB*DD*4);
  P.Ksr   = (float*)alloc(BB*DD*4);
  P.Vsr   = (float*)alloc(BB*DD*4);
  P.pws   = (float*)alloc((size_t)BB*NHH*RCH*66*4);
  P.out   = (float*)d_out;

  bf16* hbf  = P.ebf;   // h aliases e
  bf16* aout = P.qkv;   // out-proj scratch aliases qkv

  // zero s (atomic-mean target) + counters — one memset node
  hipMemsetAsync(P.s, 0, BB*DD*4 + 64, stream);

  // 12 kernel launches; no grid.sync (r13); no long-serial blocks (r14);
  // GEMM bodies inline (r16 VGPR lesson).
  k_init<<<2048, 256, 0, stream>>>(P);
  k_qkvsp<<<848, 256, 0, stream>>>(P);
  k_sat<<<MM/4, 256, 0, stream>>>(P, P.qbuf, 512, P.KeVe, P.KeVe + 512, 1024);
  k_gemm<<<256, 256, 0, stream>>>(P, P.ctxbf, P.WtO,
      P.sat_ob, P.sat_ob, P.sat_ob, P.sat_ob, P.sat_ob, aout, 512, aout, 512, 512);
  k_ln<<<MM/4, 256, 0, stream>>>(P, aout, hbf);
  k_gemm<<<1280, 256, 0, stream>>>(P, hbf, P.WtAll,
      P.sat_qb, P.sat_kb, P.sat_vb, P.rel_kb, P.rel_vb, P.qkv, 1536, P.kvbuf, 1024, 1536);
  k_relp<<<BB*NHH*RCH, 256, 0, stream>>>(P);
  k_reltail2<<<256, 256, 0, stream>>>(P);
  k_sproj1<<<32, 256, 0, stream>>>(P);
  k_sat<<<MM/4, 256, 0, stream>>>(P, P.qkv, 1536, P.qkv + 512, P.qkv + 1024, 1536);
  k_gemm<<<256, 256, 0, stream>>>(P, P.ctxbf, P.WtO,
      P.sat_ob, P.sat_ob, P.sat_ob, P.sat_ob, P.sat_ob, aout, 512, aout, 512, 512);
  k_logits<<<64, 256, 0, stream>>>(P);
}